// Round 1
// baseline (43.154 us; speedup 1.0000x reference)
//
#include <hip/hip_runtime.h>

// Problem: N=256, A=1024, B=128, C=16
//   act = inp @ theta.reshape(1024, 2048)            [256, 2048] fp32
//   d[i,j,b] = sum_c |act[j,b,c] - act[i,b,c]|
//   mb[j,b]  = (sum_i exp(-d[i,j,b]) - 1) / 255
//   out = concat([inp, mb], axis=1)                  [256, 1152] fp32

#define NN 256
#define AA 1024
#define BB 128
#define CC 16
#define NB 2048        // B*C
#define OUTW 1152      // A + B

// ---------------------------------------------------------------------------
// Kernel 1: fp32 GEMM, split-K=2. Tiles BM=32, BN=64, BK=32, 256 threads,
// 2x4 microtile. Writes partials: part[s][n][col], s in {0,1}.
// Grid: (2048/64, 256/32, 2) = (32, 8, 2) = 512 blocks.
// ---------------------------------------------------------------------------
__global__ __launch_bounds__(256) void gemm_kernel(const float* __restrict__ inp,
                                                   const float* __restrict__ theta,
                                                   float* __restrict__ part) {
    const int tid = threadIdx.x;
    const int bn = blockIdx.x;     // N tile (64 wide)
    const int bm = blockIdx.y;     // M tile (32 tall)
    const int ks = blockIdx.z;     // K split (512 each)
    const int row0 = bm * 32;
    const int col0 = bn * 64;
    const int k0base = ks * 512;

    __shared__ float As[32][32];   // [k][m]  (A transposed)
    __shared__ float Bs[32][64];   // [k][n]

    const int tx = tid & 15;       // n direction (4 cols each)
    const int ty = tid >> 4;       // m direction (2 rows each)

    float acc[2][4] = {{0.f, 0.f, 0.f, 0.f}, {0.f, 0.f, 0.f, 0.f}};

    for (int kt = 0; kt < 16; ++kt) {
        const int k0 = k0base + kt * 32;
        // Stage A tile (32 rows x 32 k): 256 float4, one per thread; store transposed.
        {
            const int m = tid >> 3, k4 = tid & 7;
            const float4 av = *reinterpret_cast<const float4*>(inp + (row0 + m) * AA + k0 + k4 * 4);
            As[k4 * 4 + 0][m] = av.x;
            As[k4 * 4 + 1][m] = av.y;
            As[k4 * 4 + 2][m] = av.z;
            As[k4 * 4 + 3][m] = av.w;
        }
        // Stage B tile (32 k x 64 cols): 512 float4, two per thread.
        #pragma unroll
        for (int r = 0; r < 2; ++r) {
            const int v = tid + r * 256;
            const int k = v >> 4, n4 = v & 15;
            const float4 bv = *reinterpret_cast<const float4*>(theta + (k0 + k) * NB + col0 + n4 * 4);
            *reinterpret_cast<float4*>(&Bs[k][n4 * 4]) = bv;
        }
        __syncthreads();
        #pragma unroll
        for (int kk = 0; kk < 32; ++kk) {
            const float a0 = As[kk][ty * 2 + 0];
            const float a1 = As[kk][ty * 2 + 1];
            const float4 b = *reinterpret_cast<const float4*>(&Bs[kk][tx * 4]);
            acc[0][0] = fmaf(a0, b.x, acc[0][0]);
            acc[0][1] = fmaf(a0, b.y, acc[0][1]);
            acc[0][2] = fmaf(a0, b.z, acc[0][2]);
            acc[0][3] = fmaf(a0, b.w, acc[0][3]);
            acc[1][0] = fmaf(a1, b.x, acc[1][0]);
            acc[1][1] = fmaf(a1, b.y, acc[1][1]);
            acc[1][2] = fmaf(a1, b.z, acc[1][2]);
            acc[1][3] = fmaf(a1, b.w, acc[1][3]);
        }
        __syncthreads();
    }

    float* p = part + (size_t)ks * (NN * NB);
    #pragma unroll
    for (int r = 0; r < 2; ++r) {
        const int row = row0 + ty * 2 + r;
        const float4 v = make_float4(acc[r][0], acc[r][1], acc[r][2], acc[r][3]);
        *reinterpret_cast<float4*>(p + row * NB + col0 + tx * 4) = v;
    }
}

// ---------------------------------------------------------------------------
// Kernel 2: pairwise exp(-L1) sum. Grid (128 b, 4 j-quarters), 256 threads.
// Stages the 256x16 act column-block for kernel b into LDS (summing the two
// split-K partials on the fly). 4 threads per j, each covering 64 i values
// (interleaved i = ii*4 + q so concurrent rows alternate banks).
// ---------------------------------------------------------------------------
__global__ __launch_bounds__(256) void pair_kernel(const float* __restrict__ part,
                                                   float* __restrict__ out) {
    const int b = blockIdx.x;       // 0..127
    const int jq = blockIdx.y;      // 0..3
    const int tid = threadIdx.x;

    __shared__ float sA[NN][CC];    // 16 KiB

    const float* p0 = part;
    const float* p1 = part + (size_t)NN * NB;

    #pragma unroll
    for (int r = 0; r < 4; ++r) {
        const int v = tid + r * 256;          // float4 index, 1024 total
        const int i = v >> 2, c4 = v & 3;
        const int g = i * NB + b * CC + c4 * 4;
        const float4 x0 = *reinterpret_cast<const float4*>(p0 + g);
        const float4 x1 = *reinterpret_cast<const float4*>(p1 + g);
        const float4 s = make_float4(x0.x + x1.x, x0.y + x1.y, x0.z + x1.z, x0.w + x1.w);
        *reinterpret_cast<float4*>(&sA[i][c4 * 4]) = s;
    }
    __syncthreads();

    const int j = jq * 64 + (tid >> 2);  // this thread's output row
    const int q = tid & 3;               // i sub-stream

    float ar[CC];
    #pragma unroll
    for (int c = 0; c < CC; ++c) ar[c] = sA[j][c];

    float s = 0.f;
    for (int ii = 0; ii < 64; ++ii) {
        const int i = ii * 4 + q;        // interleaved so the 4 live rows differ
        float d = 0.f;
        #pragma unroll
        for (int c = 0; c < CC; ++c) d += fabsf(sA[i][c] - ar[c]);
        s += __expf(-d);
    }
    // reduce the 4 i-streams (lanes of one quad)
    s += __shfl_xor(s, 1);
    s += __shfl_xor(s, 2);
    if (q == 0) {
        out[j * OUTW + AA + b] = (s - 1.0f) * (1.0f / (float)(NN - 1));
    }
}

// ---------------------------------------------------------------------------
// Kernel 3: copy inp -> out[:, :1024] (float4).
// ---------------------------------------------------------------------------
__global__ __launch_bounds__(256) void copy_kernel(const float* __restrict__ inp,
                                                   float* __restrict__ out) {
    const int idx = blockIdx.x * 256 + threadIdx.x;  // 0..65535 (float4 units)
    const int n = idx >> 8;                          // 256 float4 per row
    const int a4 = idx & 255;
    const float4 v = *reinterpret_cast<const float4*>(inp + (size_t)idx * 4);
    *reinterpret_cast<float4*>(out + n * OUTW + a4 * 4) = v;
}

extern "C" void kernel_launch(void* const* d_in, const int* in_sizes, int n_in,
                              void* d_out, int out_size, void* d_ws, size_t ws_size,
                              hipStream_t stream) {
    const float* inp = (const float*)d_in[0];     // [256][1024]
    const float* theta = (const float*)d_in[1];   // [1024][2048]
    float* out = (float*)d_out;                   // [256][1152]
    float* part = (float*)d_ws;                   // 2 * 256 * 2048 f32 = 4 MiB

    gemm_kernel<<<dim3(NB / 64, NN / 32, 2), 256, 0, stream>>>(inp, theta, part);
    pair_kernel<<<dim3(BB, 4), 256, 0, stream>>>(part, out);
    copy_kernel<<<dim3((NN * AA / 4) / 256), 256, 0, stream>>>(inp, out);
}

// Round 2
// 32.532 us; speedup vs baseline: 1.3265x; 1.3265x over previous
//
#include <hip/hip_runtime.h>

// N=256, A=1024, B=128, C=16
//   act = inp @ theta.reshape(1024, 2048)            [256, 2048] fp32 (via bf16 MFMA)
//   d[i,j,b] = sum_c |act[j,b,c] - act[i,b,c]|
//   mb[j,b]  = (sum_i exp(-d[i,j,b]) - 1) / 255
//   out = concat([inp, mb], axis=1)                  [256, 1152] fp32

#define NN 256
#define AA 1024
#define BBK 128
#define CC 16
#define NBB 2048       // B*C
#define OUTW 1152      // A + B

typedef __attribute__((ext_vector_type(4))) float f32x4;
typedef __attribute__((ext_vector_type(8))) short bf16x8;
typedef __attribute__((ext_vector_type(4))) unsigned short u16x4;

__device__ __forceinline__ unsigned short f2bf(float x) {
    union { float f; unsigned u; } v; v.f = x;
    unsigned r = v.u + 0x7FFFu + ((v.u >> 16) & 1u);   // round-to-nearest-even
    return (unsigned short)(r >> 16);
}

// ---------------------------------------------------------------------------
// Kernel 1: bf16-MFMA GEMM. Tile BM=64 x BN=64, BK=64, 16 k-iters.
// 256 threads = 4 waves in a 2x2 wave grid; each wave owns a 32x32 quadrant
// (2x2 fragments of 16x16, mfma_f32_16x16x32_bf16).
// LDS: As [m][k] bf16, Bs [n][k] bf16 (scatter-transposed during staging),
// both XOR-swizzled (byte ^= (row&7)<<4) so frag ds_read_b128 is conflict-free.
// Grid (32 bn, 4 bm) = 128 blocks. Output act fp32 in ws.
// ---------------------------------------------------------------------------
__global__ __launch_bounds__(256) void gemm_kernel(const float* __restrict__ inp,
                                                   const float* __restrict__ theta,
                                                   float* __restrict__ act) {
    const int tid = threadIdx.x;
    const int lane = tid & 63;
    const int w = tid >> 6;
    const int wm = w >> 1, wn = w & 1;
    const int col0 = blockIdx.x * 64;
    const int row0 = blockIdx.y * 64;

    __shared__ unsigned short As[64 * 64];   // 8 KiB, [m][k] (row stride 128 B)
    __shared__ unsigned short Bs[64 * 64];   // 8 KiB, [n][k]

    f32x4 acc[2][2] = {};

    for (int kt = 0; kt < 16; ++kt) {
        const int k0 = kt * 64;
        // --- stage A: 64 m x 64 k fp32 -> bf16, linear rows, swizzled ---
        #pragma unroll
        for (int r = 0; r < 4; ++r) {
            const int v = tid + r * 256;
            const int m = v >> 4, k4 = (v & 15) * 4;
            const f32x4 a = *reinterpret_cast<const f32x4*>(inp + (row0 + m) * AA + k0 + k4);
            u16x4 h;
            h.x = f2bf(a.x); h.y = f2bf(a.y); h.z = f2bf(a.z); h.w = f2bf(a.w);
            const int byt = (m * 128 + k4 * 2) ^ ((m & 7) << 4);
            *reinterpret_cast<u16x4*>(reinterpret_cast<char*>(As) + byt) = h;
        }
        // --- stage B: 64 k x 64 n fp32 -> bf16 transposed into [n][k] ---
        #pragma unroll
        for (int r = 0; r < 4; ++r) {
            const int v = tid + r * 256;
            const int k = v >> 4, n4 = (v & 15) * 4;
            const f32x4 bv = *reinterpret_cast<const f32x4*>(theta + (k0 + k) * NBB + col0 + n4);
            const float* bf = reinterpret_cast<const float*>(&bv);
            #pragma unroll
            for (int c = 0; c < 4; ++c) {
                const int n = n4 + c;
                const int byt = (n * 128 + k * 2) ^ ((n & 7) << 4);
                *reinterpret_cast<unsigned short*>(reinterpret_cast<char*>(Bs) + byt) = f2bf(bf[c]);
            }
        }
        __syncthreads();
        #pragma unroll
        for (int ks = 0; ks < 2; ++ks) {
            // k element = ks*32 + (lane>>4)*8  ->  byte offset within row:
            const int kbyte = ks * 64 + (lane >> 4) * 16;
            bf16x8 af[2], bfr[2];
            #pragma unroll
            for (int mi = 0; mi < 2; ++mi) {
                const int m = wm * 32 + mi * 16 + (lane & 15);
                const int byt = (m * 128 + kbyte) ^ ((m & 7) << 4);
                af[mi] = *reinterpret_cast<bf16x8*>(reinterpret_cast<char*>(As) + byt);
            }
            #pragma unroll
            for (int ni = 0; ni < 2; ++ni) {
                const int n = wn * 32 + ni * 16 + (lane & 15);
                const int byt = (n * 128 + kbyte) ^ ((n & 7) << 4);
                bfr[ni] = *reinterpret_cast<bf16x8*>(reinterpret_cast<char*>(Bs) + byt);
            }
            #pragma unroll
            for (int mi = 0; mi < 2; ++mi)
                #pragma unroll
                for (int ni = 0; ni < 2; ++ni)
                    acc[mi][ni] = __builtin_amdgcn_mfma_f32_16x16x32_bf16(
                        af[mi], bfr[ni], acc[mi][ni], 0, 0, 0);
        }
        __syncthreads();
    }
    // epilogue: C/D layout col = lane&15, row = (lane>>4)*4 + reg
    #pragma unroll
    for (int mi = 0; mi < 2; ++mi)
        #pragma unroll
        for (int ni = 0; ni < 2; ++ni) {
            const int col = col0 + wn * 32 + ni * 16 + (lane & 15);
            #pragma unroll
            for (int r = 0; r < 4; ++r) {
                const int row = row0 + wm * 32 + mi * 16 + (lane >> 4) * 4 + r;
                act[row * NBB + col] = acc[mi][ni][r];
            }
        }
}

// ---------------------------------------------------------------------------
// Kernel 2: pairwise exp(-L1) + fused inp->out copy.
// Grid (128 b, 4 jq), 256 threads. Stage act[:, b*16:(b+1)*16] (256x16 fp32,
// 16 KiB) in LDS. 4 threads per j (quad), i = 4*ii + q so the 4 concurrent
// rows are distinct (2-way bank alias = free); per-quad __shfl_xor reduce.
// ---------------------------------------------------------------------------
__global__ __launch_bounds__(256) void pair_kernel(const float* __restrict__ act,
                                                   const float* __restrict__ inp,
                                                   float* __restrict__ out) {
    const int b = blockIdx.x;       // 0..127
    const int jq = blockIdx.y;      // 0..3
    const int tid = threadIdx.x;

    __shared__ float sA[NN][CC];    // 16 KiB

    // fused copy of inp -> out[:, :1024]: 65536 float4 spread over 512 blocks
    if (tid < 128) {
        const int v = (b * 4 + jq) * 128 + tid;   // 0..65535
        const int n = v >> 8, a4 = v & 255;
        const f32x4 x = *reinterpret_cast<const f32x4*>(inp + (size_t)v * 4);
        *reinterpret_cast<f32x4*>(out + n * OUTW + a4 * 4) = x;
    }

    #pragma unroll
    for (int r = 0; r < 4; ++r) {
        const int v = tid + r * 256;              // 1024 float4
        const int i = v >> 2, c4 = (v & 3) * 4;
        *reinterpret_cast<f32x4*>(&sA[i][c4]) =
            *reinterpret_cast<const f32x4*>(act + i * NBB + b * CC + c4);
    }
    __syncthreads();

    const int j = jq * 64 + (tid >> 2);
    const int q = tid & 3;

    float ar[CC];
    #pragma unroll
    for (int c = 0; c < CC; ++c) ar[c] = sA[j][c];

    float s = 0.f;
    for (int ii = 0; ii < 64; ++ii) {
        const int i = ii * 4 + q;
        float d = 0.f;
        #pragma unroll
        for (int c = 0; c < CC; ++c) d += fabsf(sA[i][c] - ar[c]);
        s += __expf(-d);
    }
    s += __shfl_xor(s, 1);
    s += __shfl_xor(s, 2);
    if (q == 0) {
        out[j * OUTW + AA + b] = (s - 1.0f) * (1.0f / (float)(NN - 1));
    }
}

extern "C" void kernel_launch(void* const* d_in, const int* in_sizes, int n_in,
                              void* d_out, int out_size, void* d_ws, size_t ws_size,
                              hipStream_t stream) {
    const float* inp = (const float*)d_in[0];     // [256][1024]
    const float* theta = (const float*)d_in[1];   // [1024][2048]
    float* out = (float*)d_out;                   // [256][1152]
    float* act = (float*)d_ws;                    // 256*2048 f32 = 2 MiB

    gemm_kernel<<<dim3(32, 4), 256, 0, stream>>>(inp, theta, act);
    pair_kernel<<<dim3(BBK, 4), 256, 0, stream>>>(act, inp, out);
}

// Round 3
// 26.479 us; speedup vs baseline: 1.6298x; 1.2286x over previous
//
#include <hip/hip_runtime.h>

// N=256, A=1024, B=128, C=16
//   act = inp @ theta.reshape(1024, 2048)            [256, 2048] (bf16 MFMA)
//   d[i,j,b] = sum_c |act[j,b,c] - act[i,b,c]|
//   mb[j,b]  = (sum_i exp(-d[i,j,b]) - 1) / 255
//   out = concat([inp, mb], axis=1)                  [256, 1152] fp32

#define NN 256
#define AA 1024
#define BBK 128
#define CC 16
#define NBB 2048       // B*C
#define OUTW 1152      // A + B

typedef __attribute__((ext_vector_type(4))) float f32x4;
typedef __attribute__((ext_vector_type(8))) short bf16x8;
typedef __attribute__((ext_vector_type(4))) unsigned int u32x4;

// pack two fp32 -> two bf16 (truncation) in ONE v_perm_b32.
// result = [bf(lo), bf(hi)] little-endian.
__device__ __forceinline__ unsigned int pack_bf2(float lo, float hi) {
    union { float f; unsigned u; } a, b;
    a.f = lo; b.f = hi;
    return __builtin_amdgcn_perm(b.u, a.u, 0x07060302u);
}

// ---------------------------------------------------------------------------
// Kernel 1: bf16-MFMA GEMM, tile BM=32 x BN=64, BK=64, 16 ktiles.
// Grid (32 bn, 8 bm) = 256 blocks, 256 threads = 4 waves (2m x 2n);
// each wave computes 16x32 (1 m-frag x 2 n-frags, mfma_f32_16x16x32_bf16).
// LDS: As[32][64] bf16 [m][k], Bs[64][64] bf16 [n][k], both rows 128 B with
// XOR swizzle (byte ^= (row&7)<<4) -> frag ds_read_b128 is 2-way max.
// B staged with pack-2k b32 scatter writes (4/thread/ktile).
// Fused: copies its 32x32 patch of inp into out[:, :1024].
// ---------------------------------------------------------------------------
__global__ __launch_bounds__(256) void gemm_kernel(const float* __restrict__ inp,
                                                   const float* __restrict__ theta,
                                                   float* __restrict__ act,
                                                   float* __restrict__ out) {
    const int tid = threadIdx.x;
    const int lane = tid & 63;
    const int w = tid >> 6;
    const int wn = w & 1, wm = w >> 1;
    const int col0 = blockIdx.x * 64;   // 0..2047 step 64
    const int row0 = blockIdx.y * 32;   // 0..255  step 32

    __shared__ unsigned short As[32 * 64];  // 4 KiB
    __shared__ unsigned short Bs[64 * 64];  // 8 KiB
    char* const Asb = reinterpret_cast<char*>(As);
    char* const Bsb = reinterpret_cast<char*>(Bs);

    f32x4 acc[2] = {};

    const int am = tid >> 3;            // A stage: row m (0..31)
    const int ak8 = (tid & 7) * 8;      // 8 consecutive k

    for (int kt = 0; kt < 16; ++kt) {
        const int k0 = kt * 64;
        // --- stage A: 32 x 64 fp32 -> bf16, one b128 write per thread ---
        {
            const float* src = inp + (row0 + am) * AA + k0 + ak8;
            const f32x4 a0 = *reinterpret_cast<const f32x4*>(src);
            const f32x4 a1 = *reinterpret_cast<const f32x4*>(src + 4);
            u32x4 h;
            h.x = pack_bf2(a0.x, a0.y);
            h.y = pack_bf2(a0.z, a0.w);
            h.z = pack_bf2(a1.x, a1.y);
            h.w = pack_bf2(a1.z, a1.w);
            const int byt = (am * 128 + ak8 * 2) ^ ((am & 7) << 4);
            *reinterpret_cast<u32x4*>(Asb + byt) = h;
        }
        // --- stage B: 64 k x 64 n fp32 -> bf16 transposed into [n][k] ---
        #pragma unroll
        for (int r = 0; r < 2; ++r) {
            const int v = tid + r * 256;     // 512 tasks
            const int k2 = v >> 4;           // k-pair 0..31
            const int n4 = v & 15;           // 4 n's
            const float* s0 = theta + (k0 + k2 * 2) * NBB + col0 + n4 * 4;
            const f32x4 lo = *reinterpret_cast<const f32x4*>(s0);
            const f32x4 hi = *reinterpret_cast<const f32x4*>(s0 + NBB);
            const float* lof = reinterpret_cast<const float*>(&lo);
            const float* hif = reinterpret_cast<const float*>(&hi);
            #pragma unroll
            for (int c = 0; c < 4; ++c) {
                const int n = n4 * 4 + c;
                const int byt = (n * 128 + k2 * 4) ^ ((n & 7) << 4);
                *reinterpret_cast<unsigned int*>(Bsb + byt) = pack_bf2(lof[c], hif[c]);
            }
        }
        __syncthreads();
        #pragma unroll
        for (int ks = 0; ks < 2; ++ks) {
            const int kbyte = ks * 64 + (lane >> 4) * 16;
            const int m = wm * 16 + (lane & 15);
            const bf16x8 af = *reinterpret_cast<bf16x8*>(
                Asb + ((m * 128 + kbyte) ^ ((m & 7) << 4)));
            #pragma unroll
            for (int nf = 0; nf < 2; ++nf) {
                const int n = wn * 32 + nf * 16 + (lane & 15);
                const bf16x8 bf = *reinterpret_cast<bf16x8*>(
                    Bsb + ((n * 128 + kbyte) ^ ((n & 7) << 4)));
                acc[nf] = __builtin_amdgcn_mfma_f32_16x16x32_bf16(af, bf, acc[nf], 0, 0, 0);
            }
        }
        __syncthreads();
    }
    // epilogue: C/D layout col = lane&15, row = (lane>>4)*4 + r
    #pragma unroll
    for (int nf = 0; nf < 2; ++nf) {
        const int col = col0 + wn * 32 + nf * 16 + (lane & 15);
        #pragma unroll
        for (int r = 0; r < 4; ++r) {
            const int row = row0 + wm * 16 + (lane >> 4) * 4 + r;
            act[row * NBB + col] = acc[nf][r];
        }
    }
    // fused copy: this block's 32 rows x 32 cols patch of inp -> out
    {
        const int mr = row0 + (tid >> 3);
        const int c = blockIdx.x * 32 + (tid & 7) * 4;
        *reinterpret_cast<f32x4*>(out + mr * OUTW + c) =
            *reinterpret_cast<const f32x4*>(inp + mr * AA + c);
    }
}

// ---------------------------------------------------------------------------
// Kernel 2: pairwise exp(-L1), j-register-blocked (Jt=4).
// Grid (128 b, 4 jq) = 512 blocks, 256 threads. Stage act[:, b*16:(b+1)*16]
// (256x16 fp32) in LDS with rows padded to 20 floats (2-way alias max).
// Thread (jg, q): owns j = jq*64 + jg*4 + {0..3} (ar[4][16] in VGPRs),
// i = ii*16 + q (16 i's). LDS read per (i, 4j) = 64 B -> traffic /4.
// 16-way __shfl_xor reduce over q, q==0 writes 4 outputs.
// ---------------------------------------------------------------------------
__global__ __launch_bounds__(256) void pair_kernel(const float* __restrict__ act,
                                                   float* __restrict__ out) {
    const int b = blockIdx.x;       // 0..127
    const int jq = blockIdx.y;      // 0..3
    const int tid = threadIdx.x;

    __shared__ float sA[NN * 20];   // 20 KiB, padded rows

    #pragma unroll
    for (int r = 0; r < 4; ++r) {
        const int v = tid + r * 256;          // 1024 f32x4 tasks
        const int i = v >> 2, c4 = v & 3;
        *reinterpret_cast<f32x4*>(sA + i * 20 + c4 * 4) =
            *reinterpret_cast<const f32x4*>(act + i * NBB + b * CC + c4 * 4);
    }
    __syncthreads();

    const int jg = tid >> 4;        // 0..15
    const int q = tid & 15;         // 0..15
    const int j0 = jq * 64 + jg * 4;

    float ar[4][16];
    #pragma unroll
    for (int jj = 0; jj < 4; ++jj)
        #pragma unroll
        for (int c = 0; c < 16; ++c)
            ar[jj][c] = sA[(j0 + jj) * 20 + c];

    float s[4] = {0.f, 0.f, 0.f, 0.f};
    #pragma unroll 2
    for (int ii = 0; ii < 16; ++ii) {
        const float* row = sA + (ii * 16 + q) * 20;
        float rv[16];
        #pragma unroll
        for (int c4 = 0; c4 < 4; ++c4)
            *reinterpret_cast<f32x4*>(rv + c4 * 4) =
                *reinterpret_cast<const f32x4*>(row + c4 * 4);
        #pragma unroll
        for (int jj = 0; jj < 4; ++jj) {
            float d = 0.f;
            #pragma unroll
            for (int c = 0; c < 16; ++c) d += fabsf(rv[c] - ar[jj][c]);
            s[jj] += __expf(-d);
        }
    }
    #pragma unroll
    for (int jj = 0; jj < 4; ++jj) {
        s[jj] += __shfl_xor(s[jj], 1);
        s[jj] += __shfl_xor(s[jj], 2);
        s[jj] += __shfl_xor(s[jj], 4);
        s[jj] += __shfl_xor(s[jj], 8);
    }
    if (q == 0) {
        #pragma unroll
        for (int jj = 0; jj < 4; ++jj)
            out[(j0 + jj) * OUTW + AA + b] = (s[jj] - 1.0f) * (1.0f / 255.0f);
    }
}

extern "C" void kernel_launch(void* const* d_in, const int* in_sizes, int n_in,
                              void* d_out, int out_size, void* d_ws, size_t ws_size,
                              hipStream_t stream) {
    const float* inp = (const float*)d_in[0];     // [256][1024]
    const float* theta = (const float*)d_in[1];   // [1024][2048]
    float* out = (float*)d_out;                   // [256][1152]
    float* act = (float*)d_ws;                    // 256*2048 f32 = 2 MiB

    gemm_kernel<<<dim3(32, 8), 256, 0, stream>>>(inp, theta, act, out);
    pair_kernel<<<dim3(BBK, 4), 256, 0, stream>>>(act, out);
}